// Round 1
// baseline (172.660 us; speedup 1.0000x reference)
//
#include <hip/hip_runtime.h>

#define BATCH   131072
#define NHID    128
#define KDIM    256     // n_in + n_hid
#define BM      64      // batch rows per block
#define TPB     512     // 8 waves

typedef __bf16 bf16x8 __attribute__((ext_vector_type(8)));
typedef float  f32x4  __attribute__((ext_vector_type(4)));

__device__ __forceinline__ unsigned short f2bf(float f) {
    unsigned int u = __float_as_uint(f);
    u += 0x7FFFu + ((u >> 16) & 1u);   // RNE
    return (unsigned short)(u >> 16);
}
__device__ __forceinline__ unsigned int pack2(float a, float b) {
    return (unsigned int)f2bf(a) | ((unsigned int)f2bf(b) << 16);
}
__device__ __forceinline__ float fsigmoid(float v) { return 1.0f / (1.0f + __expf(-v)); }
__device__ __forceinline__ float ftanh(float v)    { return 2.0f / (1.0f + __expf(-2.0f * v)) - 1.0f; }

// Pack W4p[p][k] (bf16) with p = w*64 + t*16 + c  ->  gate t, output col j = w*16 + c.
// This puts all 4 gates of an output column into the same lane's 4 col-fragments.
__global__ void prep_kernel(const float* __restrict__ Wf, const float* __restrict__ Wi,
                            const float* __restrict__ Wc, const float* __restrict__ Wo,
                            const float* __restrict__ bfp, const float* __restrict__ bip,
                            const float* __restrict__ bcp, const float* __restrict__ bop,
                            const float* __restrict__ Wfc,
                            unsigned short* __restrict__ W4p, float* __restrict__ b4p,
                            unsigned short* __restrict__ Wfcb)
{
    int id = blockIdx.x * 256 + threadIdx.x;
    if (id < 512 * 256) {
        int p = id >> 8, k = id & 255;
        int w = p >> 6, t = (p >> 4) & 3, c = p & 15;
        int j = w * 16 + c;
        const float* W = (t == 0) ? Wf : (t == 1) ? Wi : (t == 2) ? Wc : Wo;
        W4p[id] = f2bf(W[j * 256 + k]);
        if (k == 0) {
            const float* bs = (t == 0) ? bfp : (t == 1) ? bip : (t == 2) ? bcp : bop;
            b4p[p] = bs[j];
        }
    } else {
        int id2 = id - 512 * 256;
        if (id2 < 128 * 128) Wfcb[id2] = f2bf(Wfc[id2]);
    }
}

__global__ __launch_bounds__(TPB) void lstm_fused(
    const float* __restrict__ x, const float* __restrict__ hidden, const float* __restrict__ ctx,
    const unsigned short* __restrict__ W4p, const float* __restrict__ b4p,
    const unsigned short* __restrict__ Wfcb, const float* __restrict__ bfc,
    float* __restrict__ out, float* __restrict__ hid_out, float* __restrict__ ctx_out)
{
    // As: bf16 [64][256] (XOR-swizzled), Hs: bf16 [64][128] (XOR-swizzled)
    __shared__ __align__(16) char lds[BM * KDIM * 2 + BM * NHID * 2];
    char* As = lds;
    char* Hs = lds + BM * KDIM * 2;

    const int tid  = threadIdx.x;
    const int lane = tid & 63;
    const int wv   = tid >> 6;     // 0..7
    const int l16  = lane & 15;
    const int lq   = lane >> 4;    // 0..3
    const int row0 = blockIdx.x * BM;

    // ---- stage A = [hidden | x] as bf16, swizzled (byte ^= (row&7)<<4) ----
    {
        const int r  = tid >> 3;   // 0..63
        const int cg = tid & 7;    // 32-col group
        const int c0 = cg * 32;
        const float* src = (c0 < NHID)
            ? (hidden + (size_t)(row0 + r) * NHID + c0)
            : (x      + (size_t)(row0 + r) * NHID + (c0 - NHID));
        #pragma unroll
        for (int g = 0; g < 4; ++g) {
            f32x4 v0 = *(const f32x4*)(src + g * 8);
            f32x4 v1 = *(const f32x4*)(src + g * 8 + 4);
            uint4 pk;
            pk.x = pack2(v0.x, v0.y);
            pk.y = pack2(v0.z, v0.w);
            pk.z = pack2(v1.x, v1.y);
            pk.w = pack2(v1.z, v1.w);
            const int cb = (c0 + g * 8) * 2;
            *(uint4*)(As + r * 512 + (cb ^ ((r & 7) << 4))) = pk;
        }
    }
    __syncthreads();

    // ---- GEMM1: gates[64][512 packed] ; wave tile 64 rows x 64 packed cols ----
    f32x4 acc[4][4];   // [row frag m][gate t]
    #pragma unroll
    for (int m = 0; m < 4; ++m)
        #pragma unroll
        for (int t = 0; t < 4; ++t)
            acc[m][t] = f32x4{0.f, 0.f, 0.f, 0.f};

    const unsigned short* Bp = W4p + (wv * 64 + l16) * 256 + lq * 8;
    #pragma unroll
    for (int ks = 0; ks < 8; ++ks) {
        bf16x8 a[4], b[4];
        const int kb = ks * 64 + lq * 16;
        #pragma unroll
        for (int m = 0; m < 4; ++m) {
            const int r = m * 16 + l16;
            a[m] = *(const bf16x8*)(As + r * 512 + (kb ^ ((r & 7) << 4)));
        }
        #pragma unroll
        for (int t = 0; t < 4; ++t)
            b[t] = *(const bf16x8*)(Bp + t * 16 * 256 + ks * 32);
        #pragma unroll
        for (int m = 0; m < 4; ++m)
            #pragma unroll
            for (int t = 0; t < 4; ++t)
                acc[m][t] = __builtin_amdgcn_mfma_f32_16x16x32_bf16(a[m], b[t], acc[m][t], 0, 0, 0);
    }

    // ---- fused LSTM elementwise; all 4 gates are in-lane thanks to packing ----
    const int jcol = wv * 16 + l16;
    const float bfv = b4p[wv * 64 +  0 + l16];
    const float biv = b4p[wv * 64 + 16 + l16];
    const float bcv = b4p[wv * 64 + 32 + l16];
    const float bov = b4p[wv * 64 + 48 + l16];

    #pragma unroll
    for (int m = 0; m < 4; ++m) {
        #pragma unroll
        for (int j = 0; j < 4; ++j) {
            const int r = m * 16 + lq * 4 + j;              // C/D: row=(lane>>4)*4+reg
            const size_t gidx = (size_t)(row0 + r) * NHID + jcol;
            const float fv = fsigmoid(acc[m][0][j] + bfv);
            const float iv = fsigmoid(acc[m][1][j] + biv);
            const float cv = ftanh(acc[m][2][j] + bcv);
            const float ov = fsigmoid(acc[m][3][j] + bov);
            const float cn = fv * ctx[gidx] + iv * cv;
            const float hn = ov * ftanh(cn);
            ctx_out[gidx] = cn;
            hid_out[gidx] = hn;
            *(unsigned short*)(Hs + r * 256 + ((jcol * 2) ^ ((r & 7) << 4))) = f2bf(hn);
        }
    }
    __syncthreads();

    // ---- GEMM2: out = hidden_new @ Wfc^T + bfc ; wave: 64 rows x 16 cols, K=128 ----
    f32x4 acc2[4];
    #pragma unroll
    for (int m = 0; m < 4; ++m) acc2[m] = f32x4{0.f, 0.f, 0.f, 0.f};

    const unsigned short* B2 = Wfcb + (wv * 16 + l16) * 128 + lq * 8;
    #pragma unroll
    for (int ks = 0; ks < 4; ++ks) {
        const int kb = ks * 64 + lq * 16;
        bf16x8 b2 = *(const bf16x8*)(B2 + ks * 32);
        #pragma unroll
        for (int m = 0; m < 4; ++m) {
            const int r = m * 16 + l16;
            bf16x8 a2 = *(const bf16x8*)(Hs + r * 256 + (kb ^ ((r & 7) << 4)));
            acc2[m] = __builtin_amdgcn_mfma_f32_16x16x32_bf16(a2, b2, acc2[m], 0, 0, 0);
        }
    }
    const float bo2 = bfc[wv * 16 + l16];
    #pragma unroll
    for (int m = 0; m < 4; ++m)
        #pragma unroll
        for (int j = 0; j < 4; ++j) {
            const int r = m * 16 + lq * 4 + j;
            out[(size_t)(row0 + r) * NHID + wv * 16 + l16] = acc2[m][j] + bo2;
        }
}

extern "C" void kernel_launch(void* const* d_in, const int* in_sizes, int n_in,
                              void* d_out, int out_size, void* d_ws, size_t ws_size,
                              hipStream_t stream) {
    const float* x      = (const float*)d_in[0];
    const float* hidden = (const float*)d_in[1];
    const float* ctx    = (const float*)d_in[2];
    const float* Wf     = (const float*)d_in[3];
    const float* bfp    = (const float*)d_in[4];
    const float* Wi     = (const float*)d_in[5];
    const float* bip    = (const float*)d_in[6];
    const float* Wc     = (const float*)d_in[7];
    const float* bcp    = (const float*)d_in[8];
    const float* Wo     = (const float*)d_in[9];
    const float* bop    = (const float*)d_in[10];
    const float* Wfc    = (const float*)d_in[11];
    const float* bfc    = (const float*)d_in[12];

    unsigned short* W4p  = (unsigned short*)d_ws;                              // 512*256*2 = 262144 B
    float*          b4p  = (float*)((char*)d_ws + 512 * 256 * 2);              // 2048 B
    unsigned short* Wfcb = (unsigned short*)((char*)d_ws + 512 * 256 * 2 + 2048); // 32768 B

    prep_kernel<<<576, 256, 0, stream>>>(Wf, Wi, Wc, Wo, bfp, bip, bcp, bop, Wfc,
                                         W4p, b4p, Wfcb);

    float* outp = (float*)d_out;
    lstm_fused<<<BATCH / BM, TPB, 0, stream>>>(
        x, hidden, ctx, W4p, b4p, Wfcb, bfc,
        outp,
        outp + (size_t)BATCH * NHID,
        outp + 2 * (size_t)BATCH * NHID);
}